// Round 4
// baseline (116.108 us; speedup 1.0000x reference)
//
#include <hip/hip_runtime.h>

// SplineActivation: out[b,d] = sum_k basis_k(x[b,d]) * coeffs[d,k]
// Uniform cubic B-spline closed form: 4 nonzero taps per element.
// LDS holds, per d, the 4 possible 4-tap windows pre-packed as float4
// (stride 80 B per d -> gather is ONE ds_read_b128, banks near-even).
// ROWS=64 amortizes staging 4x; loads hoisted in groups of 4 for MLP.

#define D     4096
#define B     4096
#define NB    7
#define DTILE 256
#define ROWS  64

constexpr int NDT    = D / DTILE;   // 16 d-tiles
constexpr int NRT    = B / ROWS;    // 64 row-tiles -> 1024 blocks
constexpr int STRIDE = 20;          // words per d: 4 packs * 4 words + 4 pad

__global__ __launch_bounds__(256, 4) void
spline_act_kernel(const float* __restrict__ x,
                  const float* __restrict__ coeffs,
                  float* __restrict__ out) {
    __shared__ float sc[DTILE * STRIDE];   // 20 KB

    const int bid   = blockIdx.x;
    const int dt    = bid & (NDT - 1);
    const int rowt  = bid >> 4;
    const int dbase = dt * DTILE;

    // Stage + pack: thread i owns local d = i. Writes 4 aligned float4 windows.
    {
        const int i = threadIdx.x;
        const float* crow = coeffs + (size_t)(dbase + i) * NB;
        float c0 = crow[0], c1 = crow[1], c2 = crow[2], c3 = crow[3];
        float c4 = crow[4], c5 = crow[5], c6 = crow[6];
        float* bp = &sc[i * STRIDE];
        *reinterpret_cast<float4*>(bp + 0)  = make_float4(c0, c1, c2, c3);
        *reinterpret_cast<float4*>(bp + 4)  = make_float4(c1, c2, c3, c4);
        *reinterpret_cast<float4*>(bp + 8)  = make_float4(c2, c3, c4, c5);
        *reinterpret_cast<float4*>(bp + 12) = make_float4(c3, c4, c5, c6);
    }
    __syncthreads();

    const int tid  = threadIdx.x;
    const int pos  = tid & 63;     // float4 position within 256-d segment (= lane)
    const int rsub = tid >> 6;     // which of 4 concurrent rows

    const float4* x4 = reinterpret_cast<const float4*>(x);
    float4*       o4 = reinterpret_cast<float4*>(out);

    const int rowbase = rowt * ROWS;
    const int colbase = (dbase >> 2) + pos;
    const float k6 = 1.0f / 6.0f;

#pragma unroll
    for (int g = 0; g < ROWS / 16; ++g) {          // 4 groups
        float4 xv[4];
        int    idx[4];
#pragma unroll
        for (int it = 0; it < 4; ++it) {           // hoisted loads: 4 in flight
            int row = rowbase + (g * 4 + it) * 4 + rsub;
            idx[it] = row * (D / 4) + colbase;
            xv[it]  = x4[idx[it]];
        }
#pragma unroll
        for (int it = 0; it < 4; ++it) {
            float xs[4] = {xv[it].x, xv[it].y, xv[it].z, xv[it].w};
            float r[4];
#pragma unroll
            for (int j = 0; j < 4; ++j) {
                float u = (xs[j] + 1.0f) * 2.0f;   // cell coord in [0,4]
                int c = (int)u;                    // trunc == floor (u >= 0)
                c = c > 3 ? 3 : c;                 // x == 1.0 edge
                float s = u - (float)c;

                float s2  = s * s;
                float s3  = s2 * s;
                float omt = 1.0f - s;
                float w0 = omt * omt * omt * k6;
                float w1 = (3.0f * s3 - 6.0f * s2 + 4.0f) * k6;
                float w2 = (-3.0f * s3 + 3.0f * s2 + 3.0f * s + 1.0f) * k6;
                float w3 = s3 * k6;

                int dl = 4 * pos + j;
                float4 cv = *reinterpret_cast<const float4*>(&sc[dl * STRIDE + 4 * c]);
                r[j] = w0 * cv.x + w1 * cv.y + w2 * cv.z + w3 * cv.w;
            }
            o4[idx[it]] = make_float4(r[0], r[1], r[2], r[3]);
        }
    }
}

extern "C" void kernel_launch(void* const* d_in, const int* in_sizes, int n_in,
                              void* d_out, int out_size, void* d_ws, size_t ws_size,
                              hipStream_t stream) {
    const float* x      = (const float*)d_in[0];   // (4096, 4096) fp32
    const float* coeffs = (const float*)d_in[1];   // (4096, 7) fp32
    float* out          = (float*)d_out;           // (4096, 4096) fp32

    const int grid = NDT * NRT;   // 1024 blocks x 256 threads
    spline_act_kernel<<<grid, 256, 0, stream>>>(x, coeffs, out);
}